// Round 1
// baseline (871.411 us; speedup 1.0000x reference)
//
#include <hip/hip_runtime.h>
#include <hip/hip_bf16.h>
#include <math.h>

// Problem constants (B=16, C=64, H=W=128, R=16)
#define B_  16
#define C_  64
#define H_  128
#define W_  128
#define HW_ (H_ * W_)
#define CR_ 4        // C / R
#define K9C (9 * C_) // 576
#define SEC 16       // SE mid channels

// ---------------------------------------------------------------------------
// K1: global average pool  y0[b,c] = mean(x[b,c,:,:])
// grid = B*C blocks, 256 threads
__global__ void k_mean(const float* __restrict__ x, float* __restrict__ y0) {
    int bc = blockIdx.x;
    const float4* p = (const float4*)(x + (size_t)bc * HW_);
    float s = 0.f;
    for (int i = threadIdx.x; i < HW_ / 4; i += 256) {
        float4 v = p[i];
        s += v.x + v.y + v.z + v.w;
    }
    // wave reduce (64 lanes)
    #pragma unroll
    for (int off = 32; off > 0; off >>= 1) s += __shfl_down(s, off, 64);
    __shared__ float part[4];
    int wave = threadIdx.x >> 6;
    if ((threadIdx.x & 63) == 0) part[wave] = s;
    __syncthreads();
    if (threadIdx.x == 0) {
        float t = part[0] + part[1] + part[2] + part[3];
        y0[bc] = t * (1.0f / (float)HW_);
    }
}

// ---------------------------------------------------------------------------
// K2: FC1+relu, FC2+sigmoid, build w_eff[b,o,c*9+k] = weight[o,c,k]*y[b,c*9+k]
// grid = B blocks, 256 threads
__global__ void k_att(const float* __restrict__ y0,
                      const float* __restrict__ fc_w1,
                      const float* __restrict__ fc_w2,
                      const float* __restrict__ weight,
                      float* __restrict__ w_eff) {
    int b = blockIdx.x;
    int t = threadIdx.x;
    __shared__ float sy0[C_];
    __shared__ float sh[CR_];
    __shared__ float sy[K9C];
    if (t < C_) sy0[t] = y0[b * C_ + t];
    __syncthreads();
    if (t < CR_) {
        float s = 0.f;
        for (int c = 0; c < C_; ++c) s = fmaf(fc_w1[t * C_ + c], sy0[c], s);
        sh[t] = fmaxf(s, 0.f);
    }
    __syncthreads();
    for (int i = t; i < K9C; i += 256) {
        float s = 0.f;
        #pragma unroll
        for (int j = 0; j < CR_; ++j) s = fmaf(fc_w2[i * CR_ + j], sh[j], s);
        sy[i] = 1.f / (1.f + expf(-s));
    }
    __syncthreads();
    float* we = w_eff + (size_t)b * C_ * K9C;
    for (int i = t; i < C_ * K9C; i += 256) {
        int ck = i % K9C;
        we[i] = weight[i] * sy[ck];
    }
}

// ---------------------------------------------------------------------------
// K3: SE conv1 (C_->SEC, 3x3, pad 1) + relu -> mid[b,16,H,W]
// grid = B * 64 tiles (16x16 pixels), 256 threads; thread computes 16 channels
__global__ void __launch_bounds__(256) k_se1(const float* __restrict__ x,
                                             const float* __restrict__ se_w1,
                                             float* __restrict__ mid) {
    int blk = blockIdx.x;
    int b = blk >> 6;
    int tile = blk & 63;
    int ty0 = (tile >> 3) << 4;
    int tx0 = (tile & 7) << 4;
    int t = threadIdx.x;
    int py = t >> 4, px = t & 15;
    int gy = ty0 + py, gx = tx0 + px;
    __shared__ float smem[18 * 18];
    float acc[SEC];
    #pragma unroll
    for (int o = 0; o < SEC; ++o) acc[o] = 0.f;
    const float* xb = x + ((size_t)b * C_) * HW_;
    for (int c = 0; c < C_; ++c) {
        __syncthreads();
        for (int i = t; i < 18 * 18; i += 256) {
            int iy = i / 18, ix = i % 18;
            int yy = ty0 + iy - 1, xx = tx0 + ix - 1;
            float v = 0.f;
            if (yy >= 0 && yy < H_ && xx >= 0 && xx < W_)
                v = xb[(size_t)c * HW_ + yy * W_ + xx];
            smem[i] = v;
        }
        __syncthreads();
        float xr[9];
        #pragma unroll
        for (int k = 0; k < 9; ++k)
            xr[k] = smem[(py + k / 3) * 18 + px + (k % 3)];
        #pragma unroll
        for (int o = 0; o < SEC; ++o) {
            #pragma unroll
            for (int k = 0; k < 9; ++k)
                acc[o] = fmaf(se_w1[(o * C_ + c) * 9 + k], xr[k], acc[o]);
        }
    }
    float* mb = mid + ((size_t)b * SEC) * HW_;
    #pragma unroll
    for (int o = 0; o < SEC; ++o)
        mb[(size_t)o * HW_ + gy * W_ + gx] = fmaxf(acc[o], 0.f);
}

// ---------------------------------------------------------------------------
// K4: SE conv2 (SEC->1, 3x3, pad 1) + sigmoid -> A[b, HW]
// grid = B*HW/256 blocks
__global__ void k_se2(const float* __restrict__ mid,
                      const float* __restrict__ se_w2,
                      float* __restrict__ A) {
    int idx = blockIdx.x * 256 + threadIdx.x;
    int b = idx >> 14;
    int l = idx & (HW_ - 1);
    int gy = l >> 7, gx = l & (W_ - 1);
    const float* mb = mid + ((size_t)b * SEC) * HW_;
    float s = 0.f;
    for (int c = 0; c < SEC; ++c) {
        #pragma unroll
        for (int ki = 0; ki < 3; ++ki) {
            int yy = gy + ki - 1;
            if (yy < 0 || yy >= H_) continue;
            #pragma unroll
            for (int kj = 0; kj < 3; ++kj) {
                int xx = gx + kj - 1;
                if (xx < 0 || xx >= W_) continue;
                s = fmaf(se_w2[c * 9 + ki * 3 + kj],
                         mb[(size_t)c * HW_ + yy * W_ + xx], s);
            }
        }
    }
    A[idx] = 1.f / (1.f + expf(-s));
}

// ---------------------------------------------------------------------------
// K5: main per-batch-weight conv, scaled by A.
// out[b,o,gy,gx] = A[b,l] * sum_{c,k} w_eff[b,o,c*9+k] * x[b,c,gy+ki-1,gx+kj-1]
// grid = B * 64 tiles (16x16), 256 threads; thread computes all 64 out channels.
// Weights are wave-uniform -> compiler emits s_load; inner loop pure v_fmac.
__global__ void __launch_bounds__(256) k_main(const float* __restrict__ x,
                                              const float* __restrict__ w_eff,
                                              const float* __restrict__ A,
                                              float* __restrict__ out) {
    int blk = blockIdx.x;
    int b = blk >> 6;
    int tile = blk & 63;
    int ty0 = (tile >> 3) << 4;
    int tx0 = (tile & 7) << 4;
    int t = threadIdx.x;
    int py = t >> 4, px = t & 15;
    int gy = ty0 + py, gx = tx0 + px;
    __shared__ float smem[18 * 18];
    float acc[C_];
    #pragma unroll
    for (int o = 0; o < C_; ++o) acc[o] = 0.f;
    const float* xb = x + ((size_t)b * C_) * HW_;
    const float* we = w_eff + (size_t)b * C_ * K9C;
    for (int c = 0; c < C_; ++c) {
        __syncthreads();
        for (int i = t; i < 18 * 18; i += 256) {
            int iy = i / 18, ix = i % 18;
            int yy = ty0 + iy - 1, xx = tx0 + ix - 1;
            float v = 0.f;
            if (yy >= 0 && yy < H_ && xx >= 0 && xx < W_)
                v = xb[(size_t)c * HW_ + yy * W_ + xx];
            smem[i] = v;
        }
        __syncthreads();
        float xr[9];
        #pragma unroll
        for (int k = 0; k < 9; ++k)
            xr[k] = smem[(py + k / 3) * 18 + px + (k % 3)];
        #pragma unroll
        for (int o = 0; o < C_; ++o) {
            const float* w = we + o * K9C + c * 9;  // wave-uniform address
            #pragma unroll
            for (int k = 0; k < 9; ++k)
                acc[o] = fmaf(w[k], xr[k], acc[o]);
        }
    }
    float a = A[b * HW_ + gy * W_ + gx];
    float* ob = out + ((size_t)b * C_) * HW_;
    #pragma unroll
    for (int o = 0; o < C_; ++o)
        ob[(size_t)o * HW_ + gy * W_ + gx] = acc[o] * a;
}

// ---------------------------------------------------------------------------
extern "C" void kernel_launch(void* const* d_in, const int* in_sizes, int n_in,
                              void* d_out, int out_size, void* d_ws, size_t ws_size,
                              hipStream_t stream) {
    const float* x      = (const float*)d_in[0];
    const float* weight = (const float*)d_in[1];
    const float* se_w1  = (const float*)d_in[2];
    const float* se_w2  = (const float*)d_in[3];
    const float* fc_w1  = (const float*)d_in[4];
    const float* fc_w2  = (const float*)d_in[5];
    float* out = (float*)d_out;

    float* ws = (float*)d_ws;
    float* y0    = ws;                          // B*C            = 1024
    float* w_eff = y0 + B_ * C_;                // B*C*576        = 589824
    float* mid   = w_eff + (size_t)B_ * C_ * K9C; // B*16*HW      = 4194304
    float* A     = mid + (size_t)B_ * SEC * HW_;  // B*HW         = 262144

    k_mean<<<B_ * C_, 256, 0, stream>>>(x, y0);
    k_att<<<B_, 256, 0, stream>>>(y0, fc_w1, fc_w2, weight, w_eff);
    k_se1<<<B_ * 64, 256, 0, stream>>>(x, se_w1, mid);
    k_se2<<<B_ * HW_ / 256, 256, 0, stream>>>(mid, se_w2, A);
    k_main<<<B_ * 64, 256, 0, stream>>>(x, w_eff, A, out);
}

// Round 2
// 254.041 us; speedup vs baseline: 3.4302x; 3.4302x over previous
//
#include <hip/hip_runtime.h>
#include <hip/hip_bf16.h>
#include <math.h>

#define B_  16
#define C_  64
#define H_  128
#define W_  128
#define HW_ (H_ * W_)
#define CR_ 4
#define K9C (9 * C_)   // 576
#define SEC 16
#define TW  130        // transposed buffer spatial dim (128 + 2 halo)
#define XPAD 72        // LDS pixel stride in elements (64 + 8 pad)

typedef float f32x4 __attribute__((ext_vector_type(4)));
typedef __bf16 bf16x8 __attribute__((ext_vector_type(8)));

static __device__ __forceinline__ unsigned short f2us(float f) {
    __bf16 h = (__bf16)f;
    return __builtin_bit_cast(unsigned short, h);
}

// ---------------------------------------------------------------------------
// K1: global average pool  y0[b,c] = mean(x[b,c,:,:])
__global__ void k_mean(const float* __restrict__ x, float* __restrict__ y0) {
    int bc = blockIdx.x;
    const float4* p = (const float4*)(x + (size_t)bc * HW_);
    float s = 0.f;
    for (int i = threadIdx.x; i < HW_ / 4; i += 256) {
        float4 v = p[i];
        s += v.x + v.y + v.z + v.w;
    }
    #pragma unroll
    for (int off = 32; off > 0; off >>= 1) s += __shfl_down(s, off, 64);
    __shared__ float part[4];
    int wave = threadIdx.x >> 6;
    if ((threadIdx.x & 63) == 0) part[wave] = s;
    __syncthreads();
    if (threadIdx.x == 0) {
        float t = part[0] + part[1] + part[2] + part[3];
        y0[bc] = t * (1.0f / (float)HW_);
    }
}

// ---------------------------------------------------------------------------
// K2: x (NCHW fp32) -> t (b, y', x', c) bf16 with zeroed 1-px halo border.
// grid = B*H blocks (one row each), 256 threads.
__global__ void k_tr(const float* __restrict__ x, unsigned short* __restrict__ t) {
    int blk = blockIdx.x;
    int b = blk >> 7, y = blk & 127;
    __shared__ unsigned short lds[C_ * TW];   // [c][x], x-stride 130 (2-way banks)
    int tid = threadIdx.x;
    // phase 1: coalesced read of 64 channel-rows, convert to bf16 into LDS
    for (int i = tid; i < C_ * 32; i += 256) {
        int c = i >> 5, xq = i & 31;
        float4 v = *(const float4*)(x + (((size_t)(b * C_ + c)) << 14) + (y << 7) + (xq << 2));
        unsigned int p0 = f2us(v.x) | ((unsigned int)f2us(v.y) << 16);
        unsigned int p1 = f2us(v.z) | ((unsigned int)f2us(v.w) << 16);
        *(unsigned int*)&lds[c * TW + (xq << 2)]     = p0;
        *(unsigned int*)&lds[c * TW + (xq << 2) + 2] = p1;
    }
    __syncthreads();
    // phase 2: transpose to pixel-major, channel-minor; write row y+1 of t
    size_t rowbase = ((size_t)(b * TW + y + 1)) * TW * C_;
    for (int j = tid; j < 128 * 16; j += 256) {
        int px = j >> 4, g = j & 15;
        unsigned short a0 = lds[(4 * g + 0) * TW + px];
        unsigned short a1 = lds[(4 * g + 1) * TW + px];
        unsigned short a2 = lds[(4 * g + 2) * TW + px];
        unsigned short a3 = lds[(4 * g + 3) * TW + px];
        uint2 wv;
        wv.x = a0 | ((unsigned int)a1 << 16);
        wv.y = a2 | ((unsigned int)a3 << 16);
        *(uint2*)(t + rowbase + (size_t)(px + 1) * C_ + (g << 2)) = wv;
    }
    // halo: zero columns x'=0 and x'=129 of this row
    if (tid < 16) {
        int px = (tid < 8) ? 0 : (TW - 1);
        int ch = tid & 7;
        uint4 z = {0, 0, 0, 0};
        *(uint4*)(t + rowbase + (size_t)px * C_ + ch * 8) = z;
    }
    // halo: zero full rows y'=0 / y'=129
    if (y == 0) {
        size_t base = (size_t)b * TW * TW * C_;
        uint4 z = {0, 0, 0, 0};
        for (int i = tid; i < TW * C_ / 8; i += 256)
            *(uint4*)(t + base + (size_t)i * 8) = z;
    }
    if (y == 127) {
        size_t base = ((size_t)(b * TW + TW - 1)) * TW * C_;
        uint4 z = {0, 0, 0, 0};
        for (int i = tid; i < TW * C_ / 8; i += 256)
            *(uint4*)(t + base + (size_t)i * 8) = z;
    }
}

// ---------------------------------------------------------------------------
// K3: transpose se_w1 [16][64][9] -> w1t [tap][o][c] bf16
__global__ void k_w1t(const float* __restrict__ se_w1, unsigned short* __restrict__ w1t) {
    int idx = blockIdx.x * 256 + threadIdx.x;   // < 9*16*64 = 9216
    int tap = idx >> 10, o = (idx >> 6) & 15, c = idx & 63;
    w1t[idx] = f2us(se_w1[(o * C_ + c) * 9 + tap]);
}

// ---------------------------------------------------------------------------
// K4: FC1+relu, FC2+sigmoid, build w_t[b][tap][o][c] = weight[o][c][tap]*y[c*9+tap]
__global__ void k_att(const float* __restrict__ y0,
                      const float* __restrict__ fc_w1,
                      const float* __restrict__ fc_w2,
                      const float* __restrict__ weight,
                      unsigned short* __restrict__ w_t) {
    int b = blockIdx.x;
    int t = threadIdx.x;
    __shared__ float sy0[C_];
    __shared__ float sh[CR_];
    __shared__ float sy[K9C];
    if (t < C_) sy0[t] = y0[b * C_ + t];
    __syncthreads();
    if (t < CR_) {
        float s = 0.f;
        for (int c = 0; c < C_; ++c) s = fmaf(fc_w1[t * C_ + c], sy0[c], s);
        sh[t] = fmaxf(s, 0.f);
    }
    __syncthreads();
    for (int i = t; i < K9C; i += 256) {
        float s = 0.f;
        #pragma unroll
        for (int j = 0; j < CR_; ++j) s = fmaf(fc_w2[i * CR_ + j], sh[j], s);
        sy[i] = 1.f / (1.f + expf(-s));
    }
    __syncthreads();
    unsigned short* wb = w_t + (size_t)b * 9 * C_ * C_;
    for (int i = t; i < 9 * C_ * C_; i += 256) {
        int tap = i >> 12, o = (i >> 6) & 63, c = i & 63;
        wb[i] = f2us(weight[(o * C_ + c) * 9 + tap] * sy[c * 9 + tap]);
    }
}

// ---------------------------------------------------------------------------
// K5: SE conv1 via MFMA (M=16, K=64 per tap, N=pixels) + relu -> mid NHWC bf16
__global__ void __launch_bounds__(256, 3)
k_se1(const unsigned short* __restrict__ t, const unsigned short* __restrict__ w1t,
      unsigned short* __restrict__ mid) {
    int blk = blockIdx.x;
    int b = blk >> 6, tile = blk & 63;
    int ty0 = (tile >> 3) << 4, tx0 = (tile & 7) << 4;
    int tid = threadIdx.x, lane = tid & 63, wave = tid >> 6;
    int n = lane & 15, q = lane >> 4, qc = q << 3;
    __shared__ __align__(16) unsigned short xt[18 * 18 * XPAD];
    // stage 18x18 pixel tile (all 64 channels) from t into LDS
    const unsigned short* tb = t + ((size_t)b * TW + ty0) * TW * C_ + (size_t)tx0 * C_;
    for (int i = tid; i < 18 * 18 * 8; i += 256) {
        int row = i / 144, r = i % 144, px = r >> 3, ch = r & 7;
        uint4 v = *(const uint4*)(tb + ((size_t)row * TW + px) * C_ + ch * 8);
        *(uint4*)&xt[(row * 18 + px) * XPAD + ch * 8] = v;
    }
    __syncthreads();
    f32x4 acc[4] = {};
    #pragma unroll
    for (int tap = 0; tap < 9; ++tap) {
        int ki = tap / 3, kj = tap % 3;
        int xl = n + kj;
        #pragma unroll
        for (int half = 0; half < 2; ++half) {
            int c0 = half << 5;
            uint4 au = *(const uint4*)(w1t + (tap * 16 + n) * C_ + c0 + qc);
            bf16x8 af = __builtin_bit_cast(bf16x8, au);
            #pragma unroll
            for (int j = 0; j < 4; ++j) {
                int yl = 4 * wave + j + ki;
                bf16x8 bf = *(const bf16x8*)&xt[(yl * 18 + xl) * XPAD + c0 + qc];
                acc[j] = __builtin_amdgcn_mfma_f32_16x16x32_bf16(af, bf, acc[j], 0, 0, 0);
            }
        }
    }
    // epilogue: relu, pack 4 bf16, store NHWC mid[b][y][x][16]
    #pragma unroll
    for (int j = 0; j < 4; ++j) {
        int y = ty0 + 4 * wave + j, xx = tx0 + n;
        uint2 wv;
        float v0 = fmaxf(acc[j][0], 0.f), v1 = fmaxf(acc[j][1], 0.f);
        float v2 = fmaxf(acc[j][2], 0.f), v3 = fmaxf(acc[j][3], 0.f);
        wv.x = f2us(v0) | ((unsigned int)f2us(v1) << 16);
        wv.y = f2us(v2) | ((unsigned int)f2us(v3) << 16);
        *(uint2*)(mid + (((size_t)(b << 14) + (y << 7) + xx) << 4) + (q << 2)) = wv;
    }
}

// ---------------------------------------------------------------------------
// K6: SE conv2 (16->1) + sigmoid -> A[b,HW] fp32
__global__ void k_se2(const unsigned short* __restrict__ mid,
                      const float* __restrict__ se_w2,
                      float* __restrict__ A) {
    int idx = blockIdx.x * 256 + threadIdx.x;
    int b = idx >> 14, l = idx & (HW_ - 1);
    int y = l >> 7, xx = l & 127;
    const unsigned short* mb = mid + (((size_t)b) << 14) * 16;
    float s = 0.f;
    #pragma unroll
    for (int ki = 0; ki < 3; ++ki) {
        int yy = y + ki - 1;
        if (yy < 0 || yy >= H_) continue;
        #pragma unroll
        for (int kj = 0; kj < 3; ++kj) {
            int x2 = xx + kj - 1;
            if (x2 < 0 || x2 >= W_) continue;
            const unsigned short* pp = mb + (((size_t)(yy << 7) + x2) << 4);
            bf16x8 v0 = *(const bf16x8*)pp;
            bf16x8 v1 = *(const bf16x8*)(pp + 8);
            #pragma unroll
            for (int e = 0; e < 8; ++e) {
                s = fmaf((float)v0[e], se_w2[e * 9 + ki * 3 + kj], s);
                s = fmaf((float)v1[e], se_w2[(e + 8) * 9 + ki * 3 + kj], s);
            }
        }
    }
    A[idx] = 1.f / (1.f + expf(-s));
}

// ---------------------------------------------------------------------------
// K7: main conv via MFMA: 9 tap-GEMMs, M=64, K=64, N=256 px per block.
// Per wave: 4 m-tiles x 4 n-tiles (rows) = 16 accumulators; 18 K-steps.
__global__ void __launch_bounds__(256, 3)
k_main(const unsigned short* __restrict__ t, const unsigned short* __restrict__ w_t,
       const float* __restrict__ A, float* __restrict__ out) {
    int blk = blockIdx.x;
    int b = blk >> 6, tile = blk & 63;
    int ty0 = (tile >> 3) << 4, tx0 = (tile & 7) << 4;
    int tid = threadIdx.x, lane = tid & 63, wave = tid >> 6;
    int n = lane & 15, q = lane >> 4, qc = q << 3;
    __shared__ __align__(16) unsigned short xt[18 * 18 * XPAD];
    const unsigned short* tb = t + ((size_t)b * TW + ty0) * TW * C_ + (size_t)tx0 * C_;
    for (int i = tid; i < 18 * 18 * 8; i += 256) {
        int row = i / 144, r = i % 144, px = r >> 3, ch = r & 7;
        uint4 v = *(const uint4*)(tb + ((size_t)row * TW + px) * C_ + ch * 8);
        *(uint4*)&xt[(row * 18 + px) * XPAD + ch * 8] = v;
    }
    __syncthreads();
    f32x4 acc[4][4] = {};   // [m-tile][n-tile(row)]
    const unsigned short* wb = w_t + (size_t)b * 9 * C_ * C_;
    #pragma unroll
    for (int tap = 0; tap < 9; ++tap) {
        int ki = tap / 3, kj = tap % 3;
        int xl = n + kj;
        #pragma unroll
        for (int half = 0; half < 2; ++half) {
            int c0 = half << 5;
            bf16x8 af[4];
            #pragma unroll
            for (int mt = 0; mt < 4; ++mt) {
                uint4 au = *(const uint4*)(wb + (tap << 12) + ((mt * 16 + n) << 6) + c0 + qc);
                af[mt] = __builtin_bit_cast(bf16x8, au);
            }
            #pragma unroll
            for (int j = 0; j < 4; ++j) {
                int yl = 4 * wave + j + ki;
                bf16x8 bf = *(const bf16x8*)&xt[(yl * 18 + xl) * XPAD + c0 + qc];
                #pragma unroll
                for (int mt = 0; mt < 4; ++mt)
                    acc[mt][j] = __builtin_amdgcn_mfma_f32_16x16x32_bf16(af[mt], bf, acc[mt][j], 0, 0, 0);
            }
        }
    }
    // epilogue: scale by A, store NCHW fp32
    #pragma unroll
    for (int j = 0; j < 4; ++j) {
        int y = ty0 + 4 * wave + j, xx = tx0 + n;
        float a = A[(b << 14) + (y << 7) + xx];
        #pragma unroll
        for (int mt = 0; mt < 4; ++mt) {
            #pragma unroll
            for (int r = 0; r < 4; ++r) {
                int o = (mt << 4) + (q << 2) + r;
                out[(((size_t)(b * C_ + o)) << 14) + (y << 7) + xx] = acc[mt][j][r] * a;
            }
        }
    }
}

// ---------------------------------------------------------------------------
extern "C" void kernel_launch(void* const* d_in, const int* in_sizes, int n_in,
                              void* d_out, int out_size, void* d_ws, size_t ws_size,
                              hipStream_t stream) {
    const float* x      = (const float*)d_in[0];
    const float* weight = (const float*)d_in[1];
    const float* se_w1  = (const float*)d_in[2];
    const float* se_w2  = (const float*)d_in[3];
    const float* fc_w1  = (const float*)d_in[4];
    const float* fc_w2  = (const float*)d_in[5];
    float* out = (float*)d_out;

    char* ws = (char*)d_ws;
    float* y0            = (float*)ws;                         ws += 4096;
    float* A             = (float*)ws;                         ws += (size_t)B_ * HW_ * 4;
    unsigned short* t    = (unsigned short*)ws;                ws += (size_t)B_ * TW * TW * C_ * 2 + 4096;
    unsigned short* w_t  = (unsigned short*)ws;                ws += (size_t)B_ * 9 * C_ * C_ * 2;
    unsigned short* w1t  = (unsigned short*)ws;                ws += 9 * 16 * C_ * 2;
    unsigned short* mid  = (unsigned short*)ws;

    k_mean<<<B_ * C_, 256, 0, stream>>>(x, y0);
    k_tr  <<<B_ * H_, 256, 0, stream>>>(x, t);
    k_w1t <<<36, 256, 0, stream>>>(se_w1, w1t);
    k_att <<<B_, 256, 0, stream>>>(y0, fc_w1, fc_w2, weight, w_t);
    k_se1 <<<B_ * 64, 256, 0, stream>>>(t, w1t, mid);
    k_se2 <<<B_ * HW_ / 256, 256, 0, stream>>>(mid, se_w2, A);
    k_main<<<B_ * 64, 256, 0, stream>>>(t, w_t, A, out);
}